// Round 1
// baseline (1667.190 us; speedup 1.0000x reference)
//
#include <hip/hip_runtime.h>

#define BOX   256
#define KS    9
#define HALF  4
#define NPTS  20000
#define NB    16
#define NN    32
#define NL    3
#define NLAT  8

__device__ __forceinline__ float fast_sigmoid(float x) {
    return 1.0f / (1.0f + __expf(-x));
}
__device__ __forceinline__ float fast_tanh(float x) {
    // tanh(x) = 1 - 2/(exp(2x)+1); saturates correctly for large |x|
    return 1.0f - 2.0f / (__expf(2.0f * x) + 1.0f);
}

__global__ __launch_bounds__(256) void decoder_kernel(
    const float* __restrict__ z,            // [16,8]
    const float* __restrict__ r,            // [16,3,3]
    const float* __restrict__ pos,          // [20000,3]
    const float* __restrict__ amp,          // [1]
    const float* __restrict__ linamp1_W,    // [32,4]
    const float* __restrict__ ampblock_W,   // [3,32,32]
    const float* __restrict__ ampblock_b,   // [3,32]
    const float* __restrict__ linamp2_W,    // [1,32]
    const float* __restrict__ linamp2_b,    // [1]
    const float* __restrict__ lin0_W,       // [32,10]
    const float* __restrict__ deform_W,     // [3,32,32]
    const float* __restrict__ deform_b,     // [3,32]
    const float* __restrict__ lin1a_W,      // [3,32]
    const float* __restrict__ lin1b_W,      // [3,3]
    const float* __restrict__ k2,           // [81]
    const int*   __restrict__ dflag,        // [1]
    float* __restrict__ img,                // [16,256,256]  (pre-zeroed)
    float* __restrict__ pos_def_out,        // [16,20000,3]
    float* __restrict__ res_out,            // [16,20000,3]
    float* __restrict__ amp_corr_out)       // [16,20000,1]
{
    const int tid = blockIdx.x * blockDim.x + threadIdx.x;
    if (tid >= NB * NPTS) return;
    const int b = tid / NPTS;
    const int p = tid - b * NPTS;
    const int d = *dflag;

    const float px = pos[3 * p + 0];
    const float py = pos[3 * p + 1];
    const float pz = pos[3 * p + 2];

    // ---------------- amplitude head ----------------
    float corr;
    {
        float a[NN];
        const float in3 = z[b * NLAT + (NLAT - 1)];  // z[:, -1]
        #pragma unroll
        for (int i = 0; i < NN; ++i) {
            const float* w = linamp1_W + i * 4;
            a[i] = w[0] * px + w[1] * py + w[2] * pz + w[3] * in3;
        }
        for (int l = 0; l < NL; ++l) {
            const float* W  = ampblock_W + l * NN * NN;
            const float* bb = ampblock_b + l * NN;
            float t[NN];
            #pragma unroll
            for (int i = 0; i < NN; ++i) {
                float s = bb[i];
                const float* wr = W + i * NN;
                #pragma unroll
                for (int j = 0; j < NN; ++j) s = fmaf(wr[j], a[j], s);
                t[i] = s > 0.0f ? s : 0.0f;
            }
            #pragma unroll
            for (int i = 0; i < NN; ++i) a[i] += t[i];
        }
        float s = linamp2_b[0];
        #pragma unroll
        for (int j = 0; j < NN; ++j) s = fmaf(linamp2_W[j], a[j], s);
        corr = fast_sigmoid(s);
    }

    // ---------------- deformation head ----------------
    float r0 = 0.0f, r1 = 0.0f, r2 = 0.0f;  // res (3-vector)
    if (d > 0) {
        float x[NN];
        #pragma unroll
        for (int i = 0; i < NN; ++i) {
            const float* w = lin0_W + i * 10;
            float s = w[0] * px + w[1] * py + w[2] * pz;
            #pragma unroll
            for (int k = 0; k < NLAT - 1; ++k)
                s = fmaf(w[3 + k], z[b * NLAT + k], s);
            x[i] = s;
        }
        for (int l = 0; l < NL; ++l) {
            const float* W  = deform_W + l * NN * NN;
            const float* bb = deform_b + l * NN;
            float t[NN];
            #pragma unroll
            for (int i = 0; i < NN; ++i) {
                float s = bb[i];
                const float* wr = W + i * NN;
                #pragma unroll
                for (int j = 0; j < NN; ++j) s = fmaf(wr[j], x[j], s);
                t[i] = s > 0.0f ? s : 0.0f;
            }
            #pragma unroll
            for (int i = 0; i < NN; ++i) x[i] += t[i];
        }
        float t3[3];
        #pragma unroll
        for (int i = 0; i < 3; ++i) {
            float s = 0.0f;
            const float* wr = lin1a_W + i * NN;
            #pragma unroll
            for (int j = 0; j < NN; ++j) s = fmaf(wr[j], x[j], s);
            t3[i] = fast_tanh(s);
        }
        r0 = t3[0] * lin1b_W[0] + t3[1] * lin1b_W[1] + t3[2] * lin1b_W[2];
        r1 = t3[0] * lin1b_W[3] + t3[1] * lin1b_W[4] + t3[2] * lin1b_W[5];
        r2 = t3[0] * lin1b_W[6] + t3[1] * lin1b_W[7] + t3[2] * lin1b_W[8];
    }

    const float pdx = px + r0, pdy = py + r1, pdz = pz + r2;

    // ---------------- write point outputs ----------------
    const int bp = b * NPTS + p;
    pos_def_out[3 * bp + 0] = pdx;
    pos_def_out[3 * bp + 1] = pdy;
    pos_def_out[3 * bp + 2] = pdz;
    res_out[3 * bp + 0] = r0;
    res_out[3 * bp + 1] = r1;
    res_out[3 * bp + 2] = r2;
    amp_corr_out[bp] = corr;

    // ---------------- project + splat ----------------
    const float* rb = r + b * 9;
    const float projx = rb[0] * pdx + rb[1] * pdy + rb[2] * pdz;
    const float projy = rb[3] * pdx + rb[4] * pdy + rb[5] * pdz;

    const float w_amp = amp[0] * corr;

    const int cx = (int)rintf((projx + 0.5f) * (float)(BOX - 1));
    const int cy = (int)rintf((projy + 0.5f) * (float)(BOX - 1));

    if (cx >= HALF && cx < BOX - HALF && cy >= HALF && cy < BOX - HALF) {
        // fully interior: no bounds checks
        float* base = img + ((b * BOX + cy) * BOX + cx);
        #pragma unroll
        for (int oy = -HALF; oy <= HALF; ++oy) {
            #pragma unroll
            for (int ox = -HALF; ox <= HALF; ++ox) {
                const float w = w_amp * k2[(oy + HALF) * KS + (ox + HALF)];
                atomicAdd(base + oy * BOX + ox, w);
            }
        }
    } else if (cx > -HALF - 1 + 0 - KS && cx < BOX + HALF + KS &&
               cy > -HALF - 1 - KS && cy < BOX + HALF + KS) {
        // near/partial overlap: per-tap bounds checks
        for (int oy = -HALF; oy <= HALF; ++oy) {
            const int yy = cy + oy;
            if (yy < 0 || yy >= BOX) continue;
            for (int ox = -HALF; ox <= HALF; ++ox) {
                const int xx = cx + ox;
                if (xx < 0 || xx >= BOX) continue;
                const float w = w_amp * k2[(oy + HALF) * KS + (ox + HALF)];
                atomicAdd(img + ((b * BOX + yy) * BOX + xx), w);
            }
        }
    }
    // else: entire window out of bounds — nothing to add
}

extern "C" void kernel_launch(void* const* d_in, const int* in_sizes, int n_in,
                              void* d_out, int out_size, void* d_ws, size_t ws_size,
                              hipStream_t stream) {
    const float* z          = (const float*)d_in[0];
    const float* r          = (const float*)d_in[1];
    const float* pos        = (const float*)d_in[2];
    const float* amp        = (const float*)d_in[3];
    const float* linamp1_W  = (const float*)d_in[4];
    const float* ampblock_W = (const float*)d_in[5];
    const float* ampblock_b = (const float*)d_in[6];
    const float* linamp2_W  = (const float*)d_in[7];
    const float* linamp2_b  = (const float*)d_in[8];
    const float* lin0_W     = (const float*)d_in[9];
    const float* deform_W   = (const float*)d_in[10];
    const float* deform_b   = (const float*)d_in[11];
    const float* lin1a_W    = (const float*)d_in[12];
    const float* lin1b_W    = (const float*)d_in[13];
    const float* k2         = (const float*)d_in[14];
    const int*   dflag      = (const int*)d_in[15];

    float* out = (float*)d_out;
    float* img          = out;                               // 16*256*256 = 1048576
    float* pos_def_out  = out + (size_t)NB * BOX * BOX;      // +960000
    float* res_out      = pos_def_out + (size_t)NB * NPTS * 3;
    float* amp_corr_out = res_out + (size_t)NB * NPTS * 3;

    // zero the splat image (rest of d_out is fully overwritten)
    hipMemsetAsync(img, 0, (size_t)NB * BOX * BOX * sizeof(float), stream);

    const int total = NB * NPTS;
    const int block = 256;
    const int grid  = (total + block - 1) / block;
    decoder_kernel<<<grid, block, 0, stream>>>(
        z, r, pos, amp, linamp1_W, ampblock_W, ampblock_b, linamp2_W, linamp2_b,
        lin0_W, deform_W, deform_b, lin1a_W, lin1b_W, k2, dflag,
        img, pos_def_out, res_out, amp_corr_out);
}

// Round 2
// 262.625 us; speedup vs baseline: 6.3482x; 6.3482x over previous
//
#include <hip/hip_runtime.h>

#define BOX   256
#define KS    9
#define HALF  4
#define NPTS  20000
#define NB    16
#define NN    32
#define NL    3
#define NLAT  8

#define CANW  (BOX + 2 * HALF)   // 264: canvas with halo for centers in [-4, 259]

__device__ __forceinline__ float fast_sigmoid(float x) {
    return 1.0f / (1.0f + __expf(-x));
}
__device__ __forceinline__ float fast_tanh(float x) {
    return 1.0f - 2.0f / (__expf(2.0f * x) + 1.0f);
}

// ---------------------------------------------------------------------------
// Kernel 1: per-(b,p) MLPs + projection + point outputs + 1-atomic center
// scatter into halo canvas C[16][264][264].
// ---------------------------------------------------------------------------
__global__ __launch_bounds__(256) void point_kernel(
    const float* __restrict__ z,            // [16,8]
    const float* __restrict__ r,            // [16,3,3]
    const float* __restrict__ pos,          // [20000,3]
    const float* __restrict__ amp,          // [1]
    const float* __restrict__ linamp1_W,    // [32,4]
    const float* __restrict__ ampblock_W,   // [3,32,32]
    const float* __restrict__ ampblock_b,   // [3,32]
    const float* __restrict__ linamp2_W,    // [1,32]
    const float* __restrict__ linamp2_b,    // [1]
    const float* __restrict__ lin0_W,       // [32,10]
    const float* __restrict__ deform_W,     // [3,32,32]
    const float* __restrict__ deform_b,     // [3,32]
    const float* __restrict__ lin1a_W,      // [3,32]
    const float* __restrict__ lin1b_W,      // [3,3]
    const int*   __restrict__ dflag,        // [1]
    float* __restrict__ canvas,             // [16,264,264] (pre-zeroed)
    float* __restrict__ pos_def_out,        // [16,20000,3]
    float* __restrict__ res_out,            // [16,20000,3]
    float* __restrict__ amp_corr_out)       // [16,20000,1]
{
    const int tid = blockIdx.x * blockDim.x + threadIdx.x;
    if (tid >= NB * NPTS) return;
    const int b = tid / NPTS;
    const int p = tid - b * NPTS;
    const int d = *dflag;

    const float px = pos[3 * p + 0];
    const float py = pos[3 * p + 1];
    const float pz = pos[3 * p + 2];

    // ---------------- amplitude head ----------------
    float corr;
    {
        float a[NN];
        const float in3 = z[b * NLAT + (NLAT - 1)];
        #pragma unroll
        for (int i = 0; i < NN; ++i) {
            const float* w = linamp1_W + i * 4;
            a[i] = w[0] * px + w[1] * py + w[2] * pz + w[3] * in3;
        }
        for (int l = 0; l < NL; ++l) {
            const float* W  = ampblock_W + l * NN * NN;
            const float* bb = ampblock_b + l * NN;
            float t[NN];
            #pragma unroll
            for (int i = 0; i < NN; ++i) {
                float s = bb[i];
                const float* wr = W + i * NN;
                #pragma unroll
                for (int j = 0; j < NN; ++j) s = fmaf(wr[j], a[j], s);
                t[i] = s > 0.0f ? s : 0.0f;
            }
            #pragma unroll
            for (int i = 0; i < NN; ++i) a[i] += t[i];
        }
        float s = linamp2_b[0];
        #pragma unroll
        for (int j = 0; j < NN; ++j) s = fmaf(linamp2_W[j], a[j], s);
        corr = fast_sigmoid(s);
    }

    // ---------------- deformation head ----------------
    float r0 = 0.0f, r1 = 0.0f, r2 = 0.0f;
    if (d > 0) {
        float x[NN];
        #pragma unroll
        for (int i = 0; i < NN; ++i) {
            const float* w = lin0_W + i * 10;
            float s = w[0] * px + w[1] * py + w[2] * pz;
            #pragma unroll
            for (int k = 0; k < NLAT - 1; ++k)
                s = fmaf(w[3 + k], z[b * NLAT + k], s);
            x[i] = s;
        }
        for (int l = 0; l < NL; ++l) {
            const float* W  = deform_W + l * NN * NN;
            const float* bb = deform_b + l * NN;
            float t[NN];
            #pragma unroll
            for (int i = 0; i < NN; ++i) {
                float s = bb[i];
                const float* wr = W + i * NN;
                #pragma unroll
                for (int j = 0; j < NN; ++j) s = fmaf(wr[j], x[j], s);
                t[i] = s > 0.0f ? s : 0.0f;
            }
            #pragma unroll
            for (int i = 0; i < NN; ++i) x[i] += t[i];
        }
        float t3[3];
        #pragma unroll
        for (int i = 0; i < 3; ++i) {
            float s = 0.0f;
            const float* wr = lin1a_W + i * NN;
            #pragma unroll
            for (int j = 0; j < NN; ++j) s = fmaf(wr[j], x[j], s);
            t3[i] = fast_tanh(s);
        }
        r0 = t3[0] * lin1b_W[0] + t3[1] * lin1b_W[1] + t3[2] * lin1b_W[2];
        r1 = t3[0] * lin1b_W[3] + t3[1] * lin1b_W[4] + t3[2] * lin1b_W[5];
        r2 = t3[0] * lin1b_W[6] + t3[1] * lin1b_W[7] + t3[2] * lin1b_W[8];
    }

    const float pdx = px + r0, pdy = py + r1, pdz = pz + r2;

    const int bp = b * NPTS + p;
    pos_def_out[3 * bp + 0] = pdx;
    pos_def_out[3 * bp + 1] = pdy;
    pos_def_out[3 * bp + 2] = pdz;
    res_out[3 * bp + 0] = r0;
    res_out[3 * bp + 1] = r1;
    res_out[3 * bp + 2] = r2;
    amp_corr_out[bp] = corr;

    // ---------------- project + single-atomic center scatter ----------------
    const float* rb = r + b * 9;
    const float projx = rb[0] * pdx + rb[1] * pdy + rb[2] * pdz;
    const float projy = rb[3] * pdx + rb[4] * pdy + rb[5] * pdz;

    const int cx = (int)rintf((projx + 0.5f) * (float)(BOX - 1));
    const int cy = (int)rintf((projy + 0.5f) * (float)(BOX - 1));

    if (cx >= -HALF && cx <= BOX - 1 + HALF && cy >= -HALF && cy <= BOX - 1 + HALF) {
        atomicAdd(canvas + ((size_t)b * CANW + (cy + HALF)) * CANW + (cx + HALF),
                  amp[0] * corr);
    }
}

// ---------------------------------------------------------------------------
// Kernel 2: x-direction gather conv.  T[b][y][x] = sum_i g[i]*C[b][y][x+8-i]
// for y in [0,264), x in [0,256).  g[i] = row-sum of k2 (exact separable
// factor).  Indices x..x+8 all within [0,263] -> no bounds checks.
// ---------------------------------------------------------------------------
__global__ __launch_bounds__(256) void conv_x_kernel(
    const float* __restrict__ canvas,   // [16,264,264]
    const float* __restrict__ k2,       // [81]
    float* __restrict__ tmp)            // [16,264,256]
{
    const int tid = blockIdx.x * blockDim.x + threadIdx.x;
    const int total = NB * CANW * BOX;
    if (tid >= total) return;

    float g[KS];
    #pragma unroll
    for (int i = 0; i < KS; ++i) {
        float s = 0.0f;
        #pragma unroll
        for (int j = 0; j < KS; ++j) s += k2[KS * i + j];
        g[i] = s;
    }

    const int x  = tid & (BOX - 1);
    const int by = tid >> 8;            // b*CANW + y
    const float* row = canvas + (size_t)by * CANW;

    float s = 0.0f;
    #pragma unroll
    for (int i = 0; i < KS; ++i)
        s = fmaf(g[i], row[x + (KS - 1) - i], s);
    tmp[tid] = s;
}

// ---------------------------------------------------------------------------
// Kernel 3: y-direction gather conv.  img[b][y][x] = sum_i g[i]*T[b][y+8-i][x]
// for y in [0,256).  y..y+8 within [0,263] -> no bounds checks.
// ---------------------------------------------------------------------------
__global__ __launch_bounds__(256) void conv_y_kernel(
    const float* __restrict__ tmp,      // [16,264,256]
    const float* __restrict__ k2,       // [81]
    float* __restrict__ img)            // [16,256,256]
{
    const int tid = blockIdx.x * blockDim.x + threadIdx.x;
    const int total = NB * BOX * BOX;
    if (tid >= total) return;

    float g[KS];
    #pragma unroll
    for (int i = 0; i < KS; ++i) {
        float s = 0.0f;
        #pragma unroll
        for (int j = 0; j < KS; ++j) s += k2[KS * i + j];
        g[i] = s;
    }

    const int x = tid & (BOX - 1);
    const int y = (tid >> 8) & (BOX - 1);
    const int b = tid >> 16;

    const float* base = tmp + ((size_t)b * CANW) * BOX + x;
    float s = 0.0f;
    #pragma unroll
    for (int i = 0; i < KS; ++i)
        s = fmaf(g[i], base[(y + (KS - 1) - i) * BOX], s);
    img[tid] = s;
}

extern "C" void kernel_launch(void* const* d_in, const int* in_sizes, int n_in,
                              void* d_out, int out_size, void* d_ws, size_t ws_size,
                              hipStream_t stream) {
    const float* z          = (const float*)d_in[0];
    const float* r          = (const float*)d_in[1];
    const float* pos        = (const float*)d_in[2];
    const float* amp        = (const float*)d_in[3];
    const float* linamp1_W  = (const float*)d_in[4];
    const float* ampblock_W = (const float*)d_in[5];
    const float* ampblock_b = (const float*)d_in[6];
    const float* linamp2_W  = (const float*)d_in[7];
    const float* linamp2_b  = (const float*)d_in[8];
    const float* lin0_W     = (const float*)d_in[9];
    const float* deform_W   = (const float*)d_in[10];
    const float* deform_b   = (const float*)d_in[11];
    const float* lin1a_W    = (const float*)d_in[12];
    const float* lin1b_W    = (const float*)d_in[13];
    const float* k2         = (const float*)d_in[14];
    const int*   dflag      = (const int*)d_in[15];

    float* out = (float*)d_out;
    float* img          = out;                               // 16*256*256
    float* pos_def_out  = out + (size_t)NB * BOX * BOX;
    float* res_out      = pos_def_out + (size_t)NB * NPTS * 3;
    float* amp_corr_out = res_out + (size_t)NB * NPTS * 3;

    // workspace layout
    float* canvas = (float*)d_ws;                              // [16,264,264]
    float* tmp    = canvas + (size_t)NB * CANW * CANW;         // [16,264,256]

    hipMemsetAsync(canvas, 0, (size_t)NB * CANW * CANW * sizeof(float), stream);

    {
        const int total = NB * NPTS;
        const int block = 256;
        point_kernel<<<(total + block - 1) / block, block, 0, stream>>>(
            z, r, pos, amp, linamp1_W, ampblock_W, ampblock_b, linamp2_W,
            linamp2_b, lin0_W, deform_W, deform_b, lin1a_W, lin1b_W, dflag,
            canvas, pos_def_out, res_out, amp_corr_out);
    }
    {
        const int total = NB * CANW * BOX;
        const int block = 256;
        conv_x_kernel<<<(total + block - 1) / block, block, 0, stream>>>(
            canvas, k2, tmp);
    }
    {
        const int total = NB * BOX * BOX;
        const int block = 256;
        conv_y_kernel<<<(total + block - 1) / block, block, 0, stream>>>(
            tmp, k2, img);
    }
}

// Round 3
// 155.338 us; speedup vs baseline: 10.7327x; 1.6907x over previous
//
#include <hip/hip_runtime.h>

#define BOX   256
#define KS    9
#define HALF  4
#define NPTS  20000
#define NB    16
#define NN    32
#define NL    3
#define NLAT  8
#define CANW  (BOX + 2 * HALF)   // 264

typedef _Float16 half8  __attribute__((ext_vector_type(8)));
typedef float    floatx4 __attribute__((ext_vector_type(4)));

// ---- workspace layout (bytes) ----
// [0, 18432)      : 9 padded [32][32] f16 weight matrices
//                   0:linamp1(pad k<4) 1..3:ampblock 4:lin0(pad k<10)
//                   5..7:deform 8:lin1a(pad n<3)
// [18432, 18468)  : g[9] fp32 separable 1-D kernel
// [20480, ...)    : canvas [16][264][264] fp32, then tmp [16][264][256] fp32
#define WS_CANVAS_BYTE_OFF 20480

// ---------------------------------------------------------------------------
// prep: convert/pad weights to f16, compute separable factor g[i]=sum_j k2[i][j]
// ---------------------------------------------------------------------------
__global__ __launch_bounds__(256) void prep_kernel(
    const float* __restrict__ linamp1_W, const float* __restrict__ ampblock_W,
    const float* __restrict__ lin0_W, const float* __restrict__ deform_W,
    const float* __restrict__ lin1a_W, const float* __restrict__ k2,
    _Float16* __restrict__ wh, float* __restrict__ g)
{
    const int idx = blockIdx.x * 256 + threadIdx.x;
    if (idx < 9 * 1024) {
        const int mat = idx >> 10, rem = idx & 1023;
        const int n = rem >> 5, k = rem & 31;
        float v = 0.0f;
        if (mat == 0)      { if (k < 4)  v = linamp1_W[n * 4 + k]; }
        else if (mat <= 3) { v = ampblock_W[(mat - 1) * 1024 + rem]; }
        else if (mat == 4) { if (k < 10) v = lin0_W[n * 10 + k]; }
        else if (mat <= 7) { v = deform_W[(mat - 5) * 1024 + rem]; }
        else               { if (n < 3)  v = lin1a_W[n * 32 + k]; }
        wh[idx] = (_Float16)v;
    } else if (idx < 9 * 1024 + 9) {
        const int i = idx - 9 * 1024;
        float s = 0.0f;
        #pragma unroll
        for (int j = 0; j < KS; ++j) s += k2[i * KS + j];
        g[i] = s;
    }
}

// ---------------------------------------------------------------------------
// C-layout (fp32, 2 N-tiles) -> A-layout (f16) via wave-private LDS tile.
// C/D: lane holds n=lane&15 (+16), m=quad*4+reg.  A: lane holds m=lane&15,
// k=quad*8+j.  Row stride 40 f16 (80 B) keeps ds_read_b128 16B-aligned and
// conflicts at the free 2-way level.
// ---------------------------------------------------------------------------
__device__ __forceinline__ half8 transpose_c(
    const floatx4& c0, const floatx4& c1, _Float16 (*ld)[40], int n, int quad)
{
    #pragma unroll
    for (int rr = 0; rr < 4; ++rr) {
        ld[quad * 4 + rr][n]      = (_Float16)c0[rr];
        ld[quad * 4 + rr][16 + n] = (_Float16)c1[rr];
    }
    __syncthreads();
    half8 av = *(const half8*)&ld[n][quad * 8];
    __syncthreads();
    return av;
}

__device__ __forceinline__ void res_layer(
    floatx4& c0, floatx4& c1, const _Float16* __restrict__ Wh,
    const float* __restrict__ bias, _Float16 (*ld)[40], int n, int quad)
{
    half8 av = transpose_c(c0, c1, ld, n, quad);
    half8 b0 = *(const half8*)(Wh + n * 32 + quad * 8);
    half8 b1 = *(const half8*)(Wh + (n + 16) * 32 + quad * 8);
    floatx4 zero = {0.f, 0.f, 0.f, 0.f};
    floatx4 d0 = __builtin_amdgcn_mfma_f32_16x16x32_f16(av, b0, zero, 0, 0, 0);
    floatx4 d1 = __builtin_amdgcn_mfma_f32_16x16x32_f16(av, b1, zero, 0, 0, 0);
    const float bb0 = bias[n], bb1 = bias[n + 16];
    #pragma unroll
    for (int rr = 0; rr < 4; ++rr) {
        c0[rr] += fmaxf(d0[rr] + bb0, 0.f);
        c1[rr] += fmaxf(d1[rr] + bb1, 0.f);
    }
}

// ---------------------------------------------------------------------------
// point kernel: 1 wave = 16 points.  MFMA for all 32-wide layers.
// ---------------------------------------------------------------------------
__global__ __launch_bounds__(256) void point_kernel(
    const float* __restrict__ z, const float* __restrict__ r,
    const float* __restrict__ pos, const float* __restrict__ amp,
    const float* __restrict__ ampblock_b, const float* __restrict__ linamp2_W,
    const float* __restrict__ linamp2_b, const float* __restrict__ deform_b,
    const float* __restrict__ lin1b_W, const int* __restrict__ dflag,
    const _Float16* __restrict__ wh,
    float* __restrict__ canvas, float* __restrict__ pos_def_out,
    float* __restrict__ res_out, float* __restrict__ amp_corr_out)
{
    __shared__ __align__(16) _Float16 sld[4][16][40];
    const int tid  = blockIdx.x * 256 + threadIdx.x;
    const int lane = threadIdx.x & 63;
    const int wid  = threadIdx.x >> 6;
    const int w    = tid >> 6;              // global wave id: 20000 waves
    const int n    = lane & 15;
    const int quad = lane >> 4;
    const int base_bp = w * 16;             // 16-point runs never cross batch
    const int b    = base_bp / NPTS;
    const int base_p = base_bp - b * NPTS;
    const int d = *dflag;

    _Float16 (*ld)[40] = sld[wid];

    // A-side point for this lane (m = lane&15)
    const float px = pos[3 * (base_p + n) + 0];
    const float py = pos[3 * (base_p + n) + 1];
    const float pz = pos[3 * (base_p + n) + 2];
    float zv[NLAT];
    #pragma unroll
    for (int i = 0; i < NLAT; ++i) zv[i] = z[b * NLAT + i];

    const floatx4 zero = {0.f, 0.f, 0.f, 0.f};

    // ================= amplitude head =================
    half8 af;
    #pragma unroll
    for (int j = 0; j < 8; ++j) af[j] = (_Float16)0.f;
    if (quad == 0) {
        af[0] = (_Float16)px; af[1] = (_Float16)py;
        af[2] = (_Float16)pz; af[3] = (_Float16)zv[NLAT - 1];
    }
    floatx4 ca0, ca1;
    {
        const _Float16* M0 = wh;            // linamp1 padded [32][32]
        half8 b0 = *(const half8*)(M0 + n * 32 + quad * 8);
        half8 b1 = *(const half8*)(M0 + (n + 16) * 32 + quad * 8);
        ca0 = __builtin_amdgcn_mfma_f32_16x16x32_f16(af, b0, zero, 0, 0, 0);
        ca1 = __builtin_amdgcn_mfma_f32_16x16x32_f16(af, b1, zero, 0, 0, 0);
    }
    #pragma unroll
    for (int l = 0; l < NL; ++l)
        res_layer(ca0, ca1, wh + (1 + l) * 1024, ampblock_b + l * 32, ld, n, quad);

    // linamp2 + sigmoid: quad-butterfly reduce over 32 neurons
    float corr[4];
    {
        const float w2a = linamp2_W[n], w2b = linamp2_W[n + 16];
        const float b2 = linamp2_b[0];
        #pragma unroll
        for (int rr = 0; rr < 4; ++rr) {
            float p = ca0[rr] * w2a + ca1[rr] * w2b;
            p += __shfl_xor(p, 1);
            p += __shfl_xor(p, 2);
            p += __shfl_xor(p, 4);
            p += __shfl_xor(p, 8);
            corr[rr] = 1.f / (1.f + __expf(-(p + b2)));
        }
    }

    // ================= deformation head =================
    float res_n[4] = {0.f, 0.f, 0.f, 0.f};   // res component n, for lanes n<3
    if (d > 0) {
        half8 a10;
        #pragma unroll
        for (int j = 0; j < 8; ++j) a10[j] = (_Float16)0.f;
        if (quad == 0) {
            a10[0] = (_Float16)px;    a10[1] = (_Float16)py;
            a10[2] = (_Float16)pz;    a10[3] = (_Float16)zv[0];
            a10[4] = (_Float16)zv[1]; a10[5] = (_Float16)zv[2];
            a10[6] = (_Float16)zv[3]; a10[7] = (_Float16)zv[4];
        } else if (quad == 1) {
            a10[0] = (_Float16)zv[5]; a10[1] = (_Float16)zv[6];
        }
        floatx4 cx0, cx1;
        {
            const _Float16* M4 = wh + 4 * 1024;   // lin0 padded
            half8 b0 = *(const half8*)(M4 + n * 32 + quad * 8);
            half8 b1 = *(const half8*)(M4 + (n + 16) * 32 + quad * 8);
            cx0 = __builtin_amdgcn_mfma_f32_16x16x32_f16(a10, b0, zero, 0, 0, 0);
            cx1 = __builtin_amdgcn_mfma_f32_16x16x32_f16(a10, b1, zero, 0, 0, 0);
        }
        #pragma unroll
        for (int l = 0; l < NL; ++l)
            res_layer(cx0, cx1, wh + (5 + l) * 1024, deform_b + l * 32, ld, n, quad);

        // tail: t3 = tanh(x @ lin1a.T) via one MFMA (only n<3 columns valid)
        half8 av = transpose_c(cx0, cx1, ld, n, quad);
        half8 bt = *(const half8*)(wh + 8 * 1024 + n * 32 + quad * 8);
        floatx4 d3 = __builtin_amdgcn_mfma_f32_16x16x32_f16(av, bt, zero, 0, 0, 0);
        float t3[4];
        #pragma unroll
        for (int rr = 0; rr < 4; ++rr)
            t3[rr] = 1.f - 2.f / (__expf(2.f * d3[rr]) + 1.f);

        // broadcast the 3 tanh components within each quad, apply lin1b
        const int qb = quad * 16;
        float t30[4], t31[4], t32[4];
        #pragma unroll
        for (int rr = 0; rr < 4; ++rr) {
            t30[rr] = __shfl(t3[rr], qb + 0);
            t31[rr] = __shfl(t3[rr], qb + 1);
            t32[rr] = __shfl(t3[rr], qb + 2);
        }
        if (n < 3) {
            const float l0 = lin1b_W[n * 3 + 0];
            const float l1 = lin1b_W[n * 3 + 1];
            const float l2 = lin1b_W[n * 3 + 2];
            #pragma unroll
            for (int rr = 0; rr < 4; ++rr)
                res_n[rr] = t30[rr] * l0 + t31[rr] * l1 + t32[rr] * l2;
        }
    }

    // ---- C-side point positions via shuffle from A-side lanes ----
    float ppx[4], ppy[4], ppz[4];
    #pragma unroll
    for (int rr = 0; rr < 4; ++rr) {
        ppx[rr] = __shfl(px, quad * 4 + rr);
        ppy[rr] = __shfl(py, quad * 4 + rr);
        ppz[rr] = __shfl(pz, quad * 4 + rr);
    }
    float pdn[4];
    #pragma unroll
    for (int rr = 0; rr < 4; ++rr) {
        const float pc = (n == 0) ? ppx[rr] : (n == 1) ? ppy[rr] : ppz[rr];
        pdn[rr] = pc + res_n[rr];
    }

    // ---- stores: res, pos_def (lanes n<3), amp_corr (lane n==0) ----
    if (n < 3) {
        #pragma unroll
        for (int rr = 0; rr < 4; ++rr) {
            const int bp = base_bp + quad * 4 + rr;
            res_out[bp * 3 + n]     = res_n[rr];
            pos_def_out[bp * 3 + n] = pdn[rr];
        }
    }
    if (n == 0) {
        floatx4 cv = {corr[0], corr[1], corr[2], corr[3]};
        *(floatx4*)(amp_corr_out + base_bp + quad * 4) = cv;
    }

    // ---- projection + single-atomic center scatter ----
    float pdx[4], pdy[4], pdz[4];
    const int qb2 = quad * 16;
    #pragma unroll
    for (int rr = 0; rr < 4; ++rr) {
        pdx[rr] = __shfl(pdn[rr], qb2 + 0);
        pdy[rr] = __shfl(pdn[rr], qb2 + 1);
        pdz[rr] = __shfl(pdn[rr], qb2 + 2);
    }
    if (n == 0) {
        const float* rb = r + b * 9;
        const float r00 = rb[0], r01 = rb[1], r02 = rb[2];
        const float r10 = rb[3], r11 = rb[4], r12 = rb[5];
        const float a0 = amp[0];
        #pragma unroll
        for (int rr = 0; rr < 4; ++rr) {
            const float pjx = r00 * pdx[rr] + r01 * pdy[rr] + r02 * pdz[rr];
            const float pjy = r10 * pdx[rr] + r11 * pdy[rr] + r12 * pdz[rr];
            const int cx = (int)rintf((pjx + 0.5f) * (float)(BOX - 1));
            const int cy = (int)rintf((pjy + 0.5f) * (float)(BOX - 1));
            if (cx >= -HALF && cx <= BOX - 1 + HALF &&
                cy >= -HALF && cy <= BOX - 1 + HALF) {
                atomicAdd(canvas + ((size_t)b * CANW + (cy + HALF)) * CANW + (cx + HALF),
                          a0 * corr[rr]);
            }
        }
    }
}

// ---------------------------------------------------------------------------
// separable convs (unchanged math from round 2, g precomputed)
// ---------------------------------------------------------------------------
__global__ __launch_bounds__(256) void conv_x_kernel(
    const float* __restrict__ canvas, const float* __restrict__ g,
    float* __restrict__ tmp)
{
    const int tid = blockIdx.x * blockDim.x + threadIdx.x;
    if (tid >= NB * CANW * BOX) return;
    const int x  = tid & (BOX - 1);
    const int by = tid >> 8;
    const float* row = canvas + (size_t)by * CANW;
    float s = 0.0f;
    #pragma unroll
    for (int i = 0; i < KS; ++i)
        s = fmaf(g[i], row[x + (KS - 1) - i], s);
    tmp[tid] = s;
}

__global__ __launch_bounds__(256) void conv_y_kernel(
    const float* __restrict__ tmp, const float* __restrict__ g,
    float* __restrict__ img)
{
    const int tid = blockIdx.x * blockDim.x + threadIdx.x;
    if (tid >= NB * BOX * BOX) return;
    const int x = tid & (BOX - 1);
    const int y = (tid >> 8) & (BOX - 1);
    const int b = tid >> 16;
    const float* base = tmp + ((size_t)b * CANW) * BOX + x;
    float s = 0.0f;
    #pragma unroll
    for (int i = 0; i < KS; ++i)
        s = fmaf(g[i], base[(y + (KS - 1) - i) * BOX], s);
    img[tid] = s;
}

extern "C" void kernel_launch(void* const* d_in, const int* in_sizes, int n_in,
                              void* d_out, int out_size, void* d_ws, size_t ws_size,
                              hipStream_t stream) {
    const float* z          = (const float*)d_in[0];
    const float* r          = (const float*)d_in[1];
    const float* pos        = (const float*)d_in[2];
    const float* amp        = (const float*)d_in[3];
    const float* linamp1_W  = (const float*)d_in[4];
    const float* ampblock_W = (const float*)d_in[5];
    const float* ampblock_b = (const float*)d_in[6];
    const float* linamp2_W  = (const float*)d_in[7];
    const float* linamp2_b  = (const float*)d_in[8];
    const float* lin0_W     = (const float*)d_in[9];
    const float* deform_W   = (const float*)d_in[10];
    const float* deform_b   = (const float*)d_in[11];
    const float* lin1a_W    = (const float*)d_in[12];
    const float* lin1b_W    = (const float*)d_in[13];
    const float* k2         = (const float*)d_in[14];
    const int*   dflag      = (const int*)d_in[15];

    float* out = (float*)d_out;
    float* img          = out;                               // [16,256,256]
    float* pos_def_out  = out + (size_t)NB * BOX * BOX;
    float* res_out      = pos_def_out + (size_t)NB * NPTS * 3;
    float* amp_corr_out = res_out + (size_t)NB * NPTS * 3;

    _Float16* wh = (_Float16*)d_ws;
    float* g     = (float*)((char*)d_ws + 18432);
    float* canvas = (float*)((char*)d_ws + WS_CANVAS_BYTE_OFF);      // [16,264,264]
    float* tmp    = canvas + (size_t)NB * CANW * CANW;               // [16,264,256]

    prep_kernel<<<(9 * 1024 + 9 + 255) / 256, 256, 0, stream>>>(
        linamp1_W, ampblock_W, lin0_W, deform_W, lin1a_W, k2, wh, g);

    hipMemsetAsync(canvas, 0, (size_t)NB * CANW * CANW * sizeof(float), stream);

    {
        // 320000 points / 64 per block (4 waves x 16 points) = 5000 blocks
        point_kernel<<<5000, 256, 0, stream>>>(
            z, r, pos, amp, ampblock_b, linamp2_W, linamp2_b, deform_b,
            lin1b_W, dflag, wh, canvas, pos_def_out, res_out, amp_corr_out);
    }
    {
        const int total = NB * CANW * BOX;
        conv_x_kernel<<<(total + 255) / 256, 256, 0, stream>>>(canvas, g, tmp);
    }
    {
        const int total = NB * BOX * BOX;
        conv_y_kernel<<<(total + 255) / 256, 256, 0, stream>>>(tmp, g, img);
    }
}

// Round 4
// 143.256 us; speedup vs baseline: 11.6378x; 1.0843x over previous
//
#include <hip/hip_runtime.h>

#define BOX   256
#define KS    9
#define HALF  4
#define NPTS  20000
#define NB    16
#define NN    32
#define NL    3
#define NLAT  8
#define CANW  (BOX + 2 * HALF)   // 264

typedef _Float16 half8   __attribute__((ext_vector_type(8)));
typedef float    floatx4 __attribute__((ext_vector_type(4)));

// ---- workspace layout (bytes) ----
// [0,16384)      : 8 padded [32][32] f16 weight matrices (A-operand form)
//                  0:linamp1(raw cols,pad k<4) 1..3:ampblock(perm cols)
//                  4:lin0(raw cols,pad k<10)   5..7:deform(perm cols)
// [16384,16512)  : linamp2_p[32] fp32 (perm cols)
// [16512,16896)  : lin1a_p[3][32] fp32 (perm cols)
// [16896,16932)  : g[9] fp32 separable 1-D kernel
// [20480,...)    : canvas [16][264][264] fp32
#define WH_ELEMS      8192
#define LINAMP2_OFF   16384
#define LIN1A_OFF     16512
#define G_OFF         16896
#define CANVAS_OFF    20480
#define CANVAS_F4     ((NB * CANW * CANW) / 4)   // 278784 float4 stores

// neuron permutation: B-index k -> natural neuron  pi^-1(k)
__device__ __forceinline__ int perm_inv(int k) {
    return ((k >> 2) & 1) * 16 + (k >> 3) * 4 + (k & 3);
}

// ---------------------------------------------------------------------------
// prep: zero canvas, build f16 A-operand weights (hidden layers get permuted
// columns), permuted head vectors, separable 1-D kernel g.
// ---------------------------------------------------------------------------
__global__ __launch_bounds__(256) void prep_kernel(
    const float* __restrict__ linamp1_W, const float* __restrict__ ampblock_W,
    const float* __restrict__ lin0_W, const float* __restrict__ deform_W,
    const float* __restrict__ lin1a_W, const float* __restrict__ linamp2_W,
    const float* __restrict__ k2, char* __restrict__ ws)
{
    const int idx = blockIdx.x * 256 + threadIdx.x;

    // zero the splat canvas (float4 stores)
    if (idx < CANVAS_F4) {
        floatx4 zv = {0.f, 0.f, 0.f, 0.f};
        ((floatx4*)(ws + CANVAS_OFF))[idx] = zv;
    }

    if (idx < WH_ELEMS) {
        _Float16* wh = (_Float16*)ws;
        const int mat = idx >> 10, rem = idx & 1023;
        const int m = rem >> 5, k = rem & 31;
        float v = 0.0f;
        if (mat == 0)      { if (k < 4)  v = linamp1_W[m * 4 + k]; }
        else if (mat <= 3) { v = ampblock_W[(mat - 1) * 1024 + m * 32 + perm_inv(k)]; }
        else if (mat == 4) { if (k < 10) v = lin0_W[m * 10 + k]; }
        else               { v = deform_W[(mat - 5) * 1024 + m * 32 + perm_inv(k)]; }
        wh[idx] = (_Float16)v;
    } else if (idx < WH_ELEMS + 32) {
        const int k = idx - WH_ELEMS;
        ((float*)(ws + LINAMP2_OFF))[k] = linamp2_W[perm_inv(k)];
    } else if (idx < WH_ELEMS + 32 + 96) {
        const int t = idx - (WH_ELEMS + 32);
        const int i = t >> 5, k = t & 31;
        ((float*)(ws + LIN1A_OFF))[t] = lin1a_W[i * 32 + perm_inv(k)];
    } else if (idx < WH_ELEMS + 32 + 96 + 9) {
        const int i = idx - (WH_ELEMS + 32 + 96);
        float s = 0.0f;
        #pragma unroll
        for (int j = 0; j < KS; ++j) s += k2[i * KS + j];
        ((float*)(ws + G_OFF))[i] = s;
    }
}

// ---------------------------------------------------------------------------
// point kernel: 1 wave = 16 points, no LDS, no barriers.
// Layers computed as D = W' @ x; the neuron permutation makes the C-layout
// output land exactly in B-layout slots of the same lane for the next layer.
// ---------------------------------------------------------------------------
__global__ __launch_bounds__(256) void point_kernel(
    const float* __restrict__ z, const float* __restrict__ r,
    const float* __restrict__ pos, const float* __restrict__ amp,
    const float* __restrict__ ampblock_b, const float* __restrict__ linamp2_b,
    const float* __restrict__ deform_b, const float* __restrict__ lin1b_W,
    const int* __restrict__ dflag, const char* __restrict__ ws,
    float* __restrict__ canvas, float* __restrict__ pos_def_out,
    float* __restrict__ res_out, float* __restrict__ amp_corr_out)
{
    const _Float16* wh       = (const _Float16*)ws;
    const float*    linamp2p = (const float*)(ws + LINAMP2_OFF);
    const float*    lin1ap   = (const float*)(ws + LIN1A_OFF);

    const int tid  = blockIdx.x * 256 + threadIdx.x;
    const int lane = threadIdx.x & 63;
    const int n    = lane & 15;      // point column AND weight A-row
    const int quad = lane >> 4;
    const int w    = tid >> 6;       // 20000 waves
    const int base_bp = w * 16;      // never crosses a batch (20000 % 16 == 0)
    const int b    = base_bp / NPTS;
    const int base_p = base_bp - b * NPTS;
    const int p    = base_p + n;
    const int bp   = base_bp + n;
    const int d    = *dflag;

    const float px = pos[3 * p + 0];
    const float py = pos[3 * p + 1];
    const float pz = pos[3 * p + 2];
    float zv[NLAT];
    #pragma unroll
    for (int i = 0; i < NLAT; ++i) zv[i] = z[b * NLAT + i];

    const floatx4 zero = {0.f, 0.f, 0.f, 0.f};
    const int aoff = quad * 8;       // k-offset of this lane's A/B fragment

    // ================= amplitude head =================
    float xB[8];
    {
        half8 bf;
        #pragma unroll
        for (int j = 0; j < 8; ++j) bf[j] = (_Float16)0.f;
        if (quad == 0) {
            bf[0] = (_Float16)px; bf[1] = (_Float16)py;
            bf[2] = (_Float16)pz; bf[3] = (_Float16)zv[NLAT - 1];
        }
        half8 a0 = *(const half8*)(wh + (n)      * 32 + aoff);
        half8 a1 = *(const half8*)(wh + (n + 16) * 32 + aoff);
        floatx4 c0 = __builtin_amdgcn_mfma_f32_16x16x32_f16(a0, bf, zero, 0, 0, 0);
        floatx4 c1 = __builtin_amdgcn_mfma_f32_16x16x32_f16(a1, bf, zero, 0, 0, 0);
        #pragma unroll
        for (int rr = 0; rr < 4; ++rr) { xB[rr] = c0[rr]; xB[4 + rr] = c1[rr]; }
    }
    #pragma unroll
    for (int l = 0; l < NL; ++l) {
        half8 hf;
        #pragma unroll
        for (int j = 0; j < 8; ++j) hf[j] = (_Float16)xB[j];
        const _Float16* M = wh + (1 + l) * 1024;
        half8 a0 = *(const half8*)(M + (n)      * 32 + aoff);
        half8 a1 = *(const half8*)(M + (n + 16) * 32 + aoff);
        floatx4 d0 = __builtin_amdgcn_mfma_f32_16x16x32_f16(a0, hf, zero, 0, 0, 0);
        floatx4 d1 = __builtin_amdgcn_mfma_f32_16x16x32_f16(a1, hf, zero, 0, 0, 0);
        floatx4 b0 = *(const floatx4*)(ampblock_b + l * 32 + quad * 4);
        floatx4 b1 = *(const floatx4*)(ampblock_b + l * 32 + 16 + quad * 4);
        #pragma unroll
        for (int rr = 0; rr < 4; ++rr) {
            xB[rr]     += fmaxf(d0[rr] + b0[rr], 0.f);
            xB[4 + rr] += fmaxf(d1[rr] + b1[rr], 0.f);
        }
    }
    float corr;
    {
        floatx4 wa = *(const floatx4*)(linamp2p + aoff);
        floatx4 wb = *(const floatx4*)(linamp2p + aoff + 4);
        float s = 0.f;
        #pragma unroll
        for (int rr = 0; rr < 4; ++rr) s += wa[rr] * xB[rr] + wb[rr] * xB[4 + rr];
        s += __shfl_xor(s, 16);
        s += __shfl_xor(s, 32);
        corr = 1.f / (1.f + __expf(-(s + linamp2_b[0])));
    }

    // ================= deformation head =================
    float r0 = 0.f, r1 = 0.f, r2 = 0.f;
    if (d > 0) {
        {
            half8 bf;
            #pragma unroll
            for (int j = 0; j < 8; ++j) bf[j] = (_Float16)0.f;
            if (quad == 0) {
                bf[0] = (_Float16)px;    bf[1] = (_Float16)py;
                bf[2] = (_Float16)pz;    bf[3] = (_Float16)zv[0];
                bf[4] = (_Float16)zv[1]; bf[5] = (_Float16)zv[2];
                bf[6] = (_Float16)zv[3]; bf[7] = (_Float16)zv[4];
            } else if (quad == 1) {
                bf[0] = (_Float16)zv[5]; bf[1] = (_Float16)zv[6];
            }
            const _Float16* M = wh + 4 * 1024;
            half8 a0 = *(const half8*)(M + (n)      * 32 + aoff);
            half8 a1 = *(const half8*)(M + (n + 16) * 32 + aoff);
            floatx4 c0 = __builtin_amdgcn_mfma_f32_16x16x32_f16(a0, bf, zero, 0, 0, 0);
            floatx4 c1 = __builtin_amdgcn_mfma_f32_16x16x32_f16(a1, bf, zero, 0, 0, 0);
            #pragma unroll
            for (int rr = 0; rr < 4; ++rr) { xB[rr] = c0[rr]; xB[4 + rr] = c1[rr]; }
        }
        #pragma unroll
        for (int l = 0; l < NL; ++l) {
            half8 hf;
            #pragma unroll
            for (int j = 0; j < 8; ++j) hf[j] = (_Float16)xB[j];
            const _Float16* M = wh + (5 + l) * 1024;
            half8 a0 = *(const half8*)(M + (n)      * 32 + aoff);
            half8 a1 = *(const half8*)(M + (n + 16) * 32 + aoff);
            floatx4 d0 = __builtin_amdgcn_mfma_f32_16x16x32_f16(a0, hf, zero, 0, 0, 0);
            floatx4 d1 = __builtin_amdgcn_mfma_f32_16x16x32_f16(a1, hf, zero, 0, 0, 0);
            floatx4 b0 = *(const floatx4*)(deform_b + l * 32 + quad * 4);
            floatx4 b1 = *(const floatx4*)(deform_b + l * 32 + 16 + quad * 4);
            #pragma unroll
            for (int rr = 0; rr < 4; ++rr) {
                xB[rr]     += fmaxf(d0[rr] + b0[rr], 0.f);
                xB[4 + rr] += fmaxf(d1[rr] + b1[rr], 0.f);
            }
        }
        float t3[3];
        #pragma unroll
        for (int i = 0; i < 3; ++i) {
            floatx4 wa = *(const floatx4*)(lin1ap + i * 32 + aoff);
            floatx4 wb = *(const floatx4*)(lin1ap + i * 32 + aoff + 4);
            float s = 0.f;
            #pragma unroll
            for (int rr = 0; rr < 4; ++rr) s += wa[rr] * xB[rr] + wb[rr] * xB[4 + rr];
            s += __shfl_xor(s, 16);
            s += __shfl_xor(s, 32);
            t3[i] = 1.f - 2.f / (__expf(2.f * s) + 1.f);
        }
        r0 = t3[0] * lin1b_W[0] + t3[1] * lin1b_W[1] + t3[2] * lin1b_W[2];
        r1 = t3[0] * lin1b_W[3] + t3[1] * lin1b_W[4] + t3[2] * lin1b_W[5];
        r2 = t3[0] * lin1b_W[6] + t3[1] * lin1b_W[7] + t3[2] * lin1b_W[8];
    }

    const float pdx = px + r0, pdy = py + r1, pdz = pz + r2;

    // every lane holds full results for point n (replicated x4 across quads);
    // split outputs by quad for parallel stores
    if (quad == 0) {
        pos_def_out[3 * bp + 0] = pdx;
        pos_def_out[3 * bp + 1] = pdy;
        pos_def_out[3 * bp + 2] = pdz;
    } else if (quad == 1) {
        res_out[3 * bp + 0] = r0;
        res_out[3 * bp + 1] = r1;
        res_out[3 * bp + 2] = r2;
    } else if (quad == 2) {
        amp_corr_out[bp] = corr;
    } else {
        const float* rb = r + b * 9;
        const float pjx = rb[0] * pdx + rb[1] * pdy + rb[2] * pdz;
        const float pjy = rb[3] * pdx + rb[4] * pdy + rb[5] * pdz;
        const int cx = (int)rintf((pjx + 0.5f) * (float)(BOX - 1));
        const int cy = (int)rintf((pjy + 0.5f) * (float)(BOX - 1));
        if (cx >= -HALF && cx <= BOX - 1 + HALF &&
            cy >= -HALF && cy <= BOX - 1 + HALF) {
            atomicAdd(canvas + ((size_t)b * CANW + (cy + HALF)) * CANW + (cx + HALF),
                      amp[0] * corr);
        }
    }
}

// ---------------------------------------------------------------------------
// fused separable conv: one block per (b, 16-row output stripe).
// Phase 1: x-conv 24 halo rows into LDS; phase 2: y-conv + store.
// ---------------------------------------------------------------------------
__global__ __launch_bounds__(256) void conv_kernel(
    const float* __restrict__ canvas, const float* __restrict__ gws,
    float* __restrict__ img)
{
    __shared__ float t_lds[24][256];
    const int x  = threadIdx.x;
    const int b  = blockIdx.x >> 4;
    const int y0 = (blockIdx.x & 15) * 16;

    float g[KS];
    #pragma unroll
    for (int i = 0; i < KS; ++i) g[i] = gws[i];

    const float* cb = canvas + (size_t)b * CANW * CANW;
    #pragma unroll 4
    for (int rr = 0; rr < 24; ++rr) {
        const float* row = cb + (size_t)(y0 + rr) * CANW;
        float s = 0.f;
        #pragma unroll
        for (int i = 0; i < KS; ++i) s = fmaf(g[i], row[x + (KS - 1) - i], s);
        t_lds[rr][x] = s;
    }
    __syncthreads();

    float* ib = img + ((size_t)b * BOX + y0) * BOX;
    #pragma unroll 4
    for (int yy = 0; yy < 16; ++yy) {
        float s = 0.f;
        #pragma unroll
        for (int i = 0; i < KS; ++i) s = fmaf(g[i], t_lds[yy + (KS - 1) - i][x], s);
        ib[yy * BOX + x] = s;
    }
}

extern "C" void kernel_launch(void* const* d_in, const int* in_sizes, int n_in,
                              void* d_out, int out_size, void* d_ws, size_t ws_size,
                              hipStream_t stream) {
    const float* z          = (const float*)d_in[0];
    const float* r          = (const float*)d_in[1];
    const float* pos        = (const float*)d_in[2];
    const float* amp        = (const float*)d_in[3];
    const float* linamp1_W  = (const float*)d_in[4];
    const float* ampblock_W = (const float*)d_in[5];
    const float* ampblock_b = (const float*)d_in[6];
    const float* linamp2_W  = (const float*)d_in[7];
    const float* linamp2_b  = (const float*)d_in[8];
    const float* lin0_W     = (const float*)d_in[9];
    const float* deform_W   = (const float*)d_in[10];
    const float* deform_b   = (const float*)d_in[11];
    const float* lin1a_W    = (const float*)d_in[12];
    const float* lin1b_W    = (const float*)d_in[13];
    const float* k2         = (const float*)d_in[14];
    const int*   dflag      = (const int*)d_in[15];

    float* out = (float*)d_out;
    float* img          = out;                               // [16,256,256]
    float* pos_def_out  = out + (size_t)NB * BOX * BOX;
    float* res_out      = pos_def_out + (size_t)NB * NPTS * 3;
    float* amp_corr_out = res_out + (size_t)NB * NPTS * 3;

    char*  ws     = (char*)d_ws;
    float* gws    = (float*)(ws + G_OFF);
    float* canvas = (float*)(ws + CANVAS_OFF);               // [16,264,264]

    // prep + canvas zero: grid sized for the float4 canvas clear
    prep_kernel<<<(CANVAS_F4 + 255) / 256, 256, 0, stream>>>(
        linamp1_W, ampblock_W, lin0_W, deform_W, lin1a_W, linamp2_W, k2, ws);

    // 320000 points / 16 per wave / 4 waves per block = 5000 blocks
    point_kernel<<<5000, 256, 0, stream>>>(
        z, r, pos, amp, ampblock_b, linamp2_b, deform_b, lin1b_W, dflag,
        ws, canvas, pos_def_out, res_out, amp_corr_out);

    conv_kernel<<<NB * 16, 256, 0, stream>>>(canvas, gws, img);
}